// Round 8
// baseline (559.649 us; speedup 1.0000x reference)
//
#include <hip/hip_runtime.h>

typedef __attribute__((ext_vector_type(8))) short bhalf8;
typedef __attribute__((ext_vector_type(4))) float floatx4;
typedef __attribute__((ext_vector_type(2))) float floatx2;
typedef __attribute__((ext_vector_type(4))) unsigned int uintx4;

#define MFMA16(a, b, c) __builtin_amdgcn_mfma_f32_16x16x32_bf16((a), (b), (c), 0, 0, 0)

__device__ __forceinline__ unsigned short f2bf(float f) {
  unsigned u = __builtin_bit_cast(unsigned, f);
  u += 0x7fffu + ((u >> 16) & 1u);
  return (unsigned short)(u >> 16);
}
__device__ __forceinline__ float bf2f(unsigned short h) {
  unsigned u = ((unsigned)h) << 16;
  return __builtin_bit_cast(float, u);
}

__device__ __forceinline__ void gload_lds16(const unsigned short* g, unsigned short* l) {
  __builtin_amdgcn_global_load_lds((__attribute__((address_space(1))) void*)(g),
                                   (__attribute__((address_space(3))) void*)(l), 16, 0, 0);
}

// ---------------- pack f32 -> bf16 (elementwise, 8/thread) ----------------
__global__ __launch_bounds__(256) void k_pack(const float* __restrict__ in,
                                              unsigned short* __restrict__ out, int n8) {
  int idx = blockIdx.x * blockDim.x + threadIdx.x;
  if (idx >= n8) return;
  const float* p = in + (size_t)idx * 8;
  floatx4 a = *(const floatx4*)p;
  floatx4 b = *(const floatx4*)(p + 4);
  bhalf8 r;
  r[0] = (short)f2bf(a[0]); r[1] = (short)f2bf(a[1]);
  r[2] = (short)f2bf(a[2]); r[3] = (short)f2bf(a[3]);
  r[4] = (short)f2bf(b[0]); r[5] = (short)f2bf(b[1]);
  r[6] = (short)f2bf(b[2]); r[7] = (short)f2bf(b[3]);
  *(bhalf8*)(out + (size_t)idx * 8) = r;
}

// ---------------- pack complex weight [O][I][2] f32 -> W' [2O][2I] bf16 ----
__global__ __launch_bounds__(256) void k_pack_w(const float* __restrict__ w,
                                                unsigned short* __restrict__ wp,
                                                int O, int I, float scale) {
  int idx = blockIdx.x * blockDim.x + threadIdx.x;
  int nI4 = I >> 2;
  if (idx >= O * nI4) return;
  int o = idx / nI4;
  int i4 = (idx - o * nI4) * 4;
  const float* src = w + ((size_t)o * I + i4) * 2;
  floatx4 a = *(const floatx4*)src;
  floatx4 b = *(const floatx4*)(src + 4);
  a *= scale; b *= scale;
  bhalf8 r0, r1;
  r0[0] = (short)f2bf(a[0]); r0[1] = (short)f2bf(-a[1]);
  r0[2] = (short)f2bf(a[2]); r0[3] = (short)f2bf(-a[3]);
  r0[4] = (short)f2bf(b[0]); r0[5] = (short)f2bf(-b[1]);
  r0[6] = (short)f2bf(b[2]); r0[7] = (short)f2bf(-b[3]);
  r1[0] = (short)f2bf(a[1]); r1[1] = (short)f2bf(a[0]);
  r1[2] = (short)f2bf(a[3]); r1[3] = (short)f2bf(a[2]);
  r1[4] = (short)f2bf(b[1]); r1[5] = (short)f2bf(b[0]);
  r1[6] = (short)f2bf(b[3]); r1[7] = (short)f2bf(b[2]);
  size_t I2 = (size_t)I * 2;
  *(bhalf8*)(wp + (size_t)(2 * o) * I2 + 2 * i4) = r0;
  *(bhalf8*)(wp + (size_t)(2 * o + 1) * I2 + 2 * i4) = r1;
}

// ---------------- concat bias [bq*s|bk|bv] -> 6144 f32 ----------------------
__global__ __launch_bounds__(256) void k_catbias(const float* __restrict__ a,
                                                 const float* __restrict__ b,
                                                 const float* __restrict__ c,
                                                 float* __restrict__ o, float qscale) {
  int i = blockIdx.x * 256 + threadIdx.x;
  float v = (i < 2048) ? a[i] * qscale : (i < 4096 ? b[i - 2048] : c[i - 4096]);
  o[i] = v;
}

// ---------------- GEMM 256x256, BK=64, 8 waves (2x4), m201 8-phase ---------
// 2 K-tiles per iter (E->buf0, O->buf1). Phase = {ds_read quadrant-subtile |
// stage | barrier | lgkmcnt(0)+sched_barrier | setprio 16 MFMA | barrier}.
// Quadrants: Q0 reads afA(8)+bfA(4), Q1 bfB(4), Q2 afB(8), Q3 none (regs live).
// Stage ledger: ph4: E+2.A(4), ph5: E+2.B(4), ph8: O+2.A+B(8).
// Counted waits: end-ph4 vmcnt(4), end-ph8 vmcnt(8) — never 0 in main loop;
// every staged half gets >=3 phases (~1800cyc) before its forced landing.
// Swizzle: slot' = slot ^ (row&7) on 128B rows — measured 0-conflict.
// Requires NT even. MODE: 0=+bias, 1=+bias+modReLU, 2=raw.
#define RD_A(dst, lsrc, half)                                                      \
  _Pragma("unroll") for (int m = 0; m < 4; ++m) {                                  \
    int p = wr * 128 + (half)*64 + m * 16 + l15;                                   \
    _Pragma("unroll") for (int kk = 0; kk < 2; ++kk)                               \
        dst[m][kk] = *(const bhalf8*)&(lsrc)[p * 64 + (((kk << 2) + l4) ^ s7) * 8]; \
  }
#define RD_B(dst, lsrc, half)                                                      \
  _Pragma("unroll") for (int n = 0; n < 2; ++n) {                                  \
    int p = wc * 64 + (half)*32 + n * 16 + l15;                                    \
    _Pragma("unroll") for (int kk = 0; kk < 2; ++kk)                               \
        dst[n][kk] = *(const bhalf8*)&(lsrc)[p * 64 + (((kk << 2) + l4) ^ s7) * 8]; \
  }
#define MM(QM, QN, afX, bfX)                                                       \
  __builtin_amdgcn_s_setprio(1);                                                   \
  _Pragma("unroll") for (int m = 0; m < 4; ++m)                                    \
      _Pragma("unroll") for (int n = 0; n < 2; ++n)                                \
          _Pragma("unroll") for (int kk = 0; kk < 2; ++kk)                         \
              acc[(QM)*4 + m][(QN)*2 + n] =                                        \
                  MFMA16(afX[m][kk], bfX[n][kk], acc[(QM)*4 + m][(QN)*2 + n]);     \
  __builtin_amdgcn_s_setprio(0);
#define LGKM0                                            \
  asm volatile("s_waitcnt lgkmcnt(0)" ::: "memory");     \
  __builtin_amdgcn_sched_barrier(0);
#define BAR __builtin_amdgcn_s_barrier();

template <int MODE>
__global__ __launch_bounds__(512, 2) void k_gemm256(
    const unsigned short* __restrict__ A0, const unsigned short* __restrict__ A1,
    int aSplit, int lda, const unsigned short* __restrict__ B, int ldb,
    const float* __restrict__ bias, unsigned short* __restrict__ C,
    int N, int K, long long zStrideC) {
  __shared__ unsigned short lds[65536];  // A0@0 A1@16384 B0@32768 B1@49152
  const int t = threadIdx.x, lane = t & 63, wid = t >> 6;
  const int wr = wid >> 2, wc = wid & 3;
  const int l15 = lane & 15, l4 = lane >> 4, s7 = l15 & 7;
  const int bn = blockIdx.x, bm = blockIdx.y, z = blockIdx.z;

  const unsigned short* Ab = ((bn < aSplit) ? A0 : A1) + (size_t)z * K;
  const unsigned short* Bb = B + (size_t)z * K;
  unsigned short* Cb = C + (size_t)z * zStrideC;

  // staging: thread t covers row pa of a 64-row round, 16B at pre-swizzled
  // col-slot ua = (t&7)^(pa&7); LDS dest linear (base + lane*16B).
  const int pa = t >> 3;
  const int ua = ((t & 7) ^ (pa & 7)) * 8;
  const unsigned short* gA = Ab + (size_t)(bm * 256 + pa) * lda + ua;
  const unsigned short* gB = Bb + (size_t)(bn * 256 + pa) * ldb + ua;

  const int NT = K >> 6, NH = NT >> 1;
  floatx4 acc[8][4];
#pragma unroll
  for (int m = 0; m < 8; ++m)
#pragma unroll
    for (int n = 0; n < 4; ++n) acc[m][n] = (floatx4)0.f;

  unsigned short* sA0 = lds + wid * 512;
  unsigned short* sA1 = lds + 16384 + wid * 512;
  unsigned short* sB0 = lds + 32768 + wid * 512;
  unsigned short* sB1 = lds + 49152 + wid * 512;

  // prologue: tile0 -> buf0 (8), tile1 -> buf1 (8); wait tile0 (vmcnt(8))
#pragma unroll
  for (int q = 0; q < 4; ++q) gload_lds16(gA + (size_t)q * 64 * lda, sA0 + q * 4096);
#pragma unroll
  for (int q = 0; q < 4; ++q) gload_lds16(gB + (size_t)q * 64 * ldb, sB0 + q * 4096);
#pragma unroll
  for (int q = 0; q < 4; ++q) gload_lds16(gA + (size_t)q * 64 * lda + 64, sA1 + q * 4096);
#pragma unroll
  for (int q = 0; q < 4; ++q) gload_lds16(gB + (size_t)q * 64 * ldb + 64, sB1 + q * 4096);
  asm volatile("s_waitcnt vmcnt(8)" ::: "memory");
  BAR

  const unsigned short* lA0 = lds;
  const unsigned short* lA1 = lds + 16384;
  const unsigned short* lB0 = lds + 32768;
  const unsigned short* lB1 = lds + 49152;
  bhalf8 afA[4][2], afB[4][2], bfA[2][2], bfB[2][2];

  for (int it = 0; it < NH; ++it) {
    const bool doS = (it + 1 < NH);
    const size_t koE = (size_t)(2 * it + 2) * 64;
    const size_t koO = (size_t)(2 * it + 3) * 64;

    // ---- ph1: E Q0 ----
    RD_A(afA, lA0, 0)
    RD_B(bfA, lB0, 0)
    asm volatile("s_waitcnt lgkmcnt(8)" ::: "memory");
    BAR LGKM0
    MM(0, 0, afA, bfA)
    BAR
    // ---- ph2: E Q1 ----
    RD_B(bfB, lB0, 1)
    BAR LGKM0
    MM(0, 1, afA, bfB)
    BAR
    // ---- ph3: E Q2 ----
    RD_A(afB, lA0, 1)
    BAR LGKM0
    MM(1, 1, afB, bfB)
    BAR
    // ---- ph4: E Q3 (stage E+2.A -> buf0) ----
    if (doS) {
#pragma unroll
      for (int q = 0; q < 4; ++q) gload_lds16(gA + (size_t)q * 64 * lda + koE, sA0 + q * 4096);
    }
    BAR
    MM(1, 0, afB, bfA)
    asm volatile("s_waitcnt vmcnt(4)" ::: "memory");
    BAR
    // ---- ph5: O Q0 (stage E+2.B -> buf0) ----
    RD_A(afA, lA1, 0)
    RD_B(bfA, lB1, 0)
    if (doS) {
#pragma unroll
      for (int q = 0; q < 4; ++q) gload_lds16(gB + (size_t)q * 64 * ldb + koE, sB0 + q * 4096);
    }
    asm volatile("s_waitcnt lgkmcnt(8)" ::: "memory");
    BAR LGKM0
    MM(0, 0, afA, bfA)
    BAR
    // ---- ph6: O Q1 ----
    RD_B(bfB, lB1, 1)
    BAR LGKM0
    MM(0, 1, afA, bfB)
    BAR
    // ---- ph7: O Q2 ----
    RD_A(afB, lA1, 1)
    BAR LGKM0
    MM(1, 1, afB, bfB)
    BAR
    // ---- ph8: O Q3 (stage O+2.A+B -> buf1) ----
    if (doS) {
#pragma unroll
      for (int q = 0; q < 4; ++q) gload_lds16(gA + (size_t)q * 64 * lda + koO, sA1 + q * 4096);
#pragma unroll
      for (int q = 0; q < 4; ++q) gload_lds16(gB + (size_t)q * 64 * ldb + koO, sB1 + q * 4096);
    }
    BAR
    MM(1, 0, afB, bfA)
    asm volatile("s_waitcnt vmcnt(8)" ::: "memory");
    BAR
  }

  const int r0 = bm * 256 + wr * 128 + l4 * 4;
  const int c0 = bn * 256 + wc * 64 + l15;
#pragma unroll
  for (int mi = 0; mi < 8; ++mi) {
    int row0 = r0 + mi * 16;
#pragma unroll
    for (int n = 0; n < 4; ++n) {
      int col = c0 + n * 16;
      float bv = (MODE == 2) ? 0.f : bias[col];
#pragma unroll
      for (int rr = 0; rr < 4; ++rr) {
        float v = acc[mi][n][rr] + bv;
        if (MODE == 1) {
          float o = __shfl_xor(v, 1, 64);
          float mag = sqrtf(v * v + o * o);
          v = (lane & 1) ? 0.5f * v : 0.5f * (v + mag);
        }
        Cb[(size_t)(row0 + rr) * N + col] = f2bf(v);
      }
    }
  }
}

// ---------------- complex flash attention (swapped QK^T, in-lane softmax) ---
// QKV fused rows: [tok][0..2047]=Q(pre-scaled), [2048..4095]=K, [4096..6143]=V.
__global__ __launch_bounds__(256) void k_attn(const unsigned short* __restrict__ qkv,
                                              unsigned short* __restrict__ O) {
  __shared__ unsigned short Ks[32][136];
  __shared__ unsigned short Vt[128][40];
  __shared__ unsigned short VtB[128][40];  // j even: -V[j+1]; j odd: V[j-1]
  __shared__ unsigned short Ps[4][2][16][40];

  const int t = threadIdx.x, lane = t & 63, wave = t >> 6;
  const int l15 = lane & 15, l4 = lane >> 4;
  const int bid = blockIdx.x;
  const int qt = bid & 7, h = (bid >> 3) & 15, b = bid >> 7;
  const int colbase = h * 128;
  const int qrow0 = b * 512 + qt * 64 + wave * 16;

  bhalf8 qf[4];
  {
    const unsigned short* qp = qkv + (size_t)(qrow0 + l15) * 6144 + colbase + l4 * 8;
#pragma unroll
    for (int ks = 0; ks < 4; ks++) qf[ks] = *(const bhalf8*)(qp + ks * 32);
  }

  float m_s[2] = {-1e30f, -1e30f}, l_s[2] = {0.f, 0.f};
  floatx4 oacc[2][8];
#pragma unroll
  for (int c = 0; c < 2; c++)
#pragma unroll
    for (int n = 0; n < 8; n++) oacc[c][n] = (floatx4)0.f;

  for (int kb = 0; kb < 16; kb++) {
    __syncthreads();
#pragma unroll
    for (int s = 0; s < 2; s++) {
      int c = t + s * 256;
      int kr = c >> 4, jc = (c & 15) * 8;
      *(bhalf8*)&Ks[kr][jc] =
          *(const bhalf8*)(qkv + (size_t)(b * 512 + kb * 32 + kr) * 6144 + 2048 + colbase + jc);
    }
#pragma unroll
    for (int s = 0; s < 2; s++) {
      int c = t + s * 256;
      int kr = c & 31, j0 = (c >> 5) * 8;
      bhalf8 vv = *(const bhalf8*)(qkv + (size_t)(b * 512 + kb * 32 + kr) * 6144 + 4096 +
                                   colbase + j0);
#pragma unroll
      for (int i2 = 0; i2 < 8; i2 += 2) {
        Vt[j0 + i2][kr] = (unsigned short)vv[i2];
        Vt[j0 + i2 + 1][kr] = (unsigned short)vv[i2 + 1];
        VtB[j0 + i2][kr] = (unsigned short)((unsigned short)vv[i2 + 1] ^ 0x8000u);
        VtB[j0 + i2 + 1][kr] = (unsigned short)vv[i2];
      }
    }
    __syncthreads();

    floatx4 sacc[2][2];
#pragma unroll
    for (int c = 0; c < 2; c++) { sacc[c][0] = (floatx4)0.f; sacc[c][1] = (floatx4)0.f; }
#pragma unroll
    for (int ks = 0; ks < 4; ks++) {
#pragma unroll
      for (int n = 0; n < 2; n++) {
        bhalf8 kf = *(const bhalf8*)&Ks[n * 16 + l15][ks * 32 + l4 * 8];
        uintx4 ku = __builtin_bit_cast(uintx4, kf);
        uintx4 kneg = ku ^ 0x80000000u;
        uintx4 kswp = (ku >> 16) | (ku << 16);
        sacc[0][n] = MFMA16(__builtin_bit_cast(bhalf8, kneg), qf[ks], sacc[0][n]);
        sacc[1][n] = MFMA16(__builtin_bit_cast(bhalf8, kswp), qf[ks], sacc[1][n]);
      }
    }

    float pmax[2];
#pragma unroll
    for (int c = 0; c < 2; c++) {
      float a = fmaxf(fmaxf(sacc[c][0][0], sacc[c][0][1]), fmaxf(sacc[c][0][2], sacc[c][0][3]));
      float d = fmaxf(fmaxf(sacc[c][1][0], sacc[c][1][1]), fmaxf(sacc[c][1][2], sacc[c][1][3]));
      float v = fmaxf(a, d);
      v = fmaxf(v, __shfl_xor(v, 16, 64));
      v = fmaxf(v, __shfl_xor(v, 32, 64));
      pmax[c] = v;
    }
    if (__any((pmax[0] > m_s[0] + 8.f) || (pmax[1] > m_s[1] + 8.f))) {
#pragma unroll
      for (int c = 0; c < 2; c++) {
        float mnew = fmaxf(m_s[c], pmax[c]);
        float cr = __expf(m_s[c] - mnew);
        l_s[c] *= cr;
        m_s[c] = mnew;
        float crq[4];
#pragma unroll
        for (int r = 0; r < 4; r++) crq[r] = __shfl(cr, l4 * 4 + r, 64);
#pragma unroll
        for (int nn = 0; nn < 8; nn++)
#pragma unroll
          for (int r = 0; r < 4; r++) oacc[c][nn][r] *= crq[r];
      }
    }
#pragma unroll
    for (int c = 0; c < 2; c++) {
      float p[8], sum = 0.f;
#pragma unroll
      for (int n = 0; n < 2; n++)
#pragma unroll
        for (int r = 0; r < 4; r++) {
          float e = __expf(sacc[c][n][r] - m_s[c]);
          p[n * 4 + r] = e;
          sum += e;
        }
      sum += __shfl_xor(sum, 16, 64);
      sum += __shfl_xor(sum, 32, 64);
      l_s[c] += sum;
#pragma unroll
      for (int n = 0; n < 2; n++) {
        unsigned pk0, pk1;
        asm("v_cvt_pk_bf16_f32 %0, %1, %2" : "=v"(pk0) : "v"(p[n * 4 + 0]), "v"(p[n * 4 + 1]));
        asm("v_cvt_pk_bf16_f32 %0, %1, %2" : "=v"(pk1) : "v"(p[n * 4 + 2]), "v"(p[n * 4 + 3]));
        *(unsigned*)&Ps[wave][c][l15][n * 16 + l4 * 4] = pk0;
        *(unsigned*)&Ps[wave][c][l15][n * 16 + l4 * 4 + 2] = pk1;
      }
    }
    asm volatile("s_waitcnt lgkmcnt(0)" ::: "memory");
    __builtin_amdgcn_sched_barrier(0);

    bhalf8 par = *(const bhalf8*)&Ps[wave][0][l15][l4 * 8];
    bhalf8 pai = *(const bhalf8*)&Ps[wave][1][l15][l4 * 8];
    __builtin_amdgcn_s_setprio(1);
#pragma unroll
    for (int nn = 0; nn < 8; nn++) {
      bhalf8 vf = *(const bhalf8*)&Vt[nn * 16 + l15][l4 * 8];
      bhalf8 vb = *(const bhalf8*)&VtB[nn * 16 + l15][l4 * 8];
      oacc[0][nn] = MFMA16(par, vf, oacc[0][nn]);
      oacc[1][nn] = MFMA16(pai, vb, oacc[1][nn]);
    }
    __builtin_amdgcn_s_setprio(0);
  }

  float inv0[4], inv1[4];
#pragma unroll
  for (int r = 0; r < 4; r++) {
    inv0[r] = 1.f / __shfl(l_s[0], l4 * 4 + r, 64);
    inv1[r] = 1.f / __shfl(l_s[1], l4 * 4 + r, 64);
  }
#pragma unroll
  for (int nn = 0; nn < 8; nn++) {
#pragma unroll
    for (int r = 0; r < 4; r++) {
      float o = oacc[0][nn][r] * inv0[r] + oacc[1][nn][r] * inv1[r];
      int row = qrow0 + l4 * 4 + r;
      int col = colbase + nn * 16 + l15;
      O[(size_t)row * 2048 + col] = f2bf(o);
    }
  }
}

// ---------------- block reduction of 4 values across 256 threads ------------
__device__ __forceinline__ void block_reduce_4(float* v, float* sbuf, int t) {
  int lane = t & 63, wave = t >> 6;
#pragma unroll
  for (int i = 0; i < 4; i++) {
    float x = v[i];
#pragma unroll
    for (int off = 32; off > 0; off >>= 1) x += __shfl_xor(x, off, 64);
    if (lane == 0) sbuf[wave * 4 + i] = x;
  }
  __syncthreads();
#pragma unroll
  for (int i = 0; i < 4; i++) v[i] = sbuf[i] + sbuf[4 + i] + sbuf[8 + i] + sbuf[12 + i];
  __syncthreads();
}

// ---------------- post-attention: (O+q) -> LN0 -> (+x) -> LN1 ---------------
__global__ __launch_bounds__(256) void k_ln_attn(const unsigned short* __restrict__ O,
                                                 const float* __restrict__ qin,
                                                 const float* __restrict__ xin,
                                                 const float* __restrict__ g,
                                                 const float* __restrict__ bb,
                                                 float* __restrict__ xr2,
                                                 unsigned short* __restrict__ xr2b) {
  __shared__ float sbuf[16];
  const int row = blockIdx.x, t = threadIdx.x;
  const size_t base = (size_t)row * 2048;
  float tr[4], ti[4], acc[4] = {0.f, 0.f, 0.f, 0.f};
#pragma unroll
  for (int k = 0; k < 4; k++) {
    int d = k * 256 + t;
    unsigned op = *(const unsigned*)(O + base + 2 * d);
    floatx2 qp = *(const floatx2*)(qin + base + 2 * d);
    float a = bf2f((unsigned short)(op & 0xffffu)) + qp[0];
    float c = bf2f((unsigned short)(op >> 16)) + qp[1];
    tr[k] = a; ti[k] = c;
    acc[0] += a; acc[1] += a * a; acc[2] += c; acc[3] += c * c;
  }
  block_reduce_4(acc, sbuf, t);
  float mr = acc[0] * (1.f / 1024.f), vr = acc[1] * (1.f / 1024.f) - mr * mr;
  float mi = acc[2] * (1.f / 1024.f), vi = acc[3] * (1.f / 1024.f) - mi * mi;
  float ir = rsqrtf(vr + 1e-5f), ii = rsqrtf(vi + 1e-5f);
  float ur[4], ui[4], a2[4] = {0.f, 0.f, 0.f, 0.f};
#pragma unroll
  for (int k = 0; k < 4; k++) {
    int d = k * 256 + t;
    float u_r = (tr[k] - mr) * ir * g[d] + bb[d];
    float u_i = (ti[k] - mi) * ii * g[1024 + d] + bb[1024 + d];
    floatx2 xp = *(const floatx2*)(xin + base + 2 * d);
    float v_r = xp[0] + u_r, v_i = xp[1] + u_i;
    ur[k] = v_r; ui[k] = v_i;
    a2[0] += v_r; a2[1] += v_r * v_r; a2[2] += v_i; a2[3] += v_i * v_i;
  }
  block_reduce_4(a2, sbuf, t);
  float mr2 = a2[0] * (1.f / 1024.f), vr2 = a2[1] * (1.f / 1024.f) - mr2 * mr2;
  float mi2 = a2[2] * (1.f / 1024.f), vi2 = a2[3] * (1.f / 1024.f) - mi2 * mi2;
  float ir2 = rsqrtf(vr2 + 1e-5f), ii2 = rsqrtf(vi2 + 1e-5f);
#pragma unroll
  for (int k = 0; k < 4; k++) {
    int d = k * 256 + t;
    float w_r = (ur[k] - mr2) * ir2 * g[2048 + d] + bb[2048 + d];
    float w_i = (ui[k] - mi2) * ii2 * g[3072 + d] + bb[3072 + d];
    floatx2 o; o[0] = w_r; o[1] = w_i;
    *(floatx2*)(xr2 + base + 2 * d) = o;
    unsigned pk = ((unsigned)f2bf(w_i) << 16) | (unsigned)f2bf(w_r);
    *(unsigned*)(xr2b + base + 2 * d) = pk;
  }
}

// ---------------- final: (xr2 + p0 + p1 + bias) -> LN2 -> out ---------------
__global__ __launch_bounds__(256) void k_ln_final(const unsigned short* __restrict__ P0,
                                                  const unsigned short* __restrict__ P1,
                                                  const float* __restrict__ xr2,
                                                  const float* __restrict__ pbias,
                                                  const float* __restrict__ g,
                                                  const float* __restrict__ bb,
                                                  float* __restrict__ out) {
  __shared__ float sbuf[16];
  const int row = blockIdx.x, t = threadIdx.x;
  const size_t base = (size_t)row * 2048;
  float tr[4], ti[4], acc[4] = {0.f, 0.f, 0.f, 0.f};
#pragma unroll
  for (int k = 0; k < 4; k++) {
    int d = k * 256 + t;
    unsigned m0 = *(const unsigned*)(P0 + base + 2 * d);
    unsigned m1 = *(const unsigned*)(P1 + base + 2 * d);
    floatx2 xp = *(const floatx2*)(xr2 + base + 2 * d);
    floatx2 bp = *(const floatx2*)(pbias + 2 * d);
    float a = xp[0] + bp[0] + bf2f((unsigned short)(m0 & 0xffffu)) +
              bf2f((unsigned short)(m1 & 0xffffu));
    float c = xp[1] + bp[1] + bf2f((unsigned short)(m0 >> 16)) +
              bf2f((unsigned short)(m1 >> 16));
    tr[k] = a; ti[k] = c;
    acc[0] += a; acc[1] += a * a; acc[2] += c; acc[3] += c * c;
  }
  block_reduce_4(acc, sbuf, t);
  float mr = acc[0] * (1.f / 1024.f), vr = acc[1] * (1.f / 1024.f) - mr * mr;
  float mi = acc[2] * (1.f / 1024.f), vi = acc[3] * (1.f / 1024.f) - mi * mi;
  float ir = rsqrtf(vr + 1e-5f), ii = rsqrtf(vi + 1e-5f);
#pragma unroll
  for (int k = 0; k < 4; k++) {
    int d = k * 256 + t;
    float w_r = (tr[k] - mr) * ir * g[4096 + d] + bb[4096 + d];
    float w_i = (ti[k] - mi) * ii * g[5120 + d] + bb[5120 + d];
    floatx2 o; o[0] = w_r; o[1] = w_i;
    *(floatx2*)(out + base + 2 * d) = o;
  }
}

extern "C" void kernel_launch(void* const* d_in, const int* in_sizes, int n_in,
                              void* d_out, int out_size, void* d_ws, size_t ws_size,
                              hipStream_t stream) {
  const float* x   = (const float*)d_in[0];
  const float* qy  = (const float*)d_in[1];
  const float* wq  = (const float*)d_in[2];
  const float* bq  = (const float*)d_in[3];
  const float* wk  = (const float*)d_in[4];
  const float* bk  = (const float*)d_in[5];
  const float* wv  = (const float*)d_in[6];
  const float* bv  = (const float*)d_in[7];
  const float* wfc = (const float*)d_in[8];
  const float* bfc = (const float*)d_in[9];
  const float* wpj = (const float*)d_in[10];
  const float* bpj = (const float*)d_in[11];
  const float* lng = (const float*)d_in[12];
  const float* lnb = (const float*)d_in[13];

  const size_t SZ_TOK = (size_t)4096 * 2048;
  unsigned short* ws0  = (unsigned short*)d_ws;
  unsigned short* xqb  = ws0;
  unsigned short* xb   = xqb + SZ_TOK;
  unsigned short* wp   = xb + SZ_TOK;
  unsigned short* QKVb = wp + 2 * SZ_TOK;
  unsigned short* hb   = QKVb + 3 * SZ_TOK;
  float* cbias = (float*)(wp + SZ_TOK + SZ_TOK / 2);
  unsigned short* Ob  = xqb;
  float*          xr2 = (float*)QKVb;
  unsigned short* x2b = QKVb + 2 * SZ_TOK;
  const int BIG = 1 << 30;

  const int n8 = (int)(SZ_TOK / 8);
  k_pack<<<n8 / 256, 256, 0, stream>>>(qy, xqb, n8);
  k_pack<<<n8 / 256, 256, 0, stream>>>(x, xb, n8);

  // fused QKV: B = [Wq'*0.125; Wk'; Wv'] (N=6144); A = xqb for bn<8, xb else
  k_pack_w<<<1024, 256, 0, stream>>>(wq, wp, 1024, 1024, 0.125f);
  k_pack_w<<<1024, 256, 0, stream>>>(wk, wp + (size_t)2048 * 2048, 1024, 1024, 1.f);
  k_pack_w<<<1024, 256, 0, stream>>>(wv, wp + (size_t)4096 * 2048, 1024, 1024, 1.f);
  k_catbias<<<24, 256, 0, stream>>>(bq, bk, bv, cbias, 0.125f);
  k_gemm256<0><<<dim3(24, 16, 1), 512, 0, stream>>>(xqb, xb, 8, 2048, wp, 2048, cbias,
                                                    QKVb, 6144, 2048, 0);

  k_attn<<<1024, 256, 0, stream>>>(QKVb, Ob);
  k_ln_attn<<<4096, 256, 0, stream>>>(Ob, qy, x, lng, lnb, xr2, x2b);

  // fc + fused modReLU: M=4096, N=8192, K=2048
  k_pack_w<<<4096, 256, 0, stream>>>(wfc, wp, 4096, 1024, 1.f);
  k_gemm256<1><<<dim3(32, 16, 1), 512, 0, stream>>>(x2b, x2b, BIG, 2048, wp, 2048, bfc,
                                                    hb, 8192, 2048, 0);

  // proj split-K=2: z in {0,1}, K=4096 each, raw bf16 partials into xqb/xb
  k_pack_w<<<4096, 256, 0, stream>>>(wpj, wp, 1024, 4096, 1.f);
  k_gemm256<2><<<dim3(8, 16, 2), 512, 0, stream>>>(hb, hb, BIG, 8192, wp, 8192, bpj,
                                                   xqb, 2048, 4096, (long long)SZ_TOK);

  k_ln_final<<<4096, 256, 0, stream>>>(xqb, xb, xr2, bpj, lng, lnb, (float*)d_out);
}

// Round 9
// 535.225 us; speedup vs baseline: 1.0456x; 1.0456x over previous
//
#include <hip/hip_runtime.h>

typedef __attribute__((ext_vector_type(8))) short bhalf8;
typedef __attribute__((ext_vector_type(4))) float floatx4;
typedef __attribute__((ext_vector_type(2))) float floatx2;
typedef __attribute__((ext_vector_type(4))) unsigned int uintx4;

#define MFMA16(a, b, c) __builtin_amdgcn_mfma_f32_16x16x32_bf16((a), (b), (c), 0, 0, 0)

__device__ __forceinline__ unsigned short f2bf(float f) {
  unsigned u = __builtin_bit_cast(unsigned, f);
  u += 0x7fffu + ((u >> 16) & 1u);
  return (unsigned short)(u >> 16);
}
__device__ __forceinline__ float bf2f(unsigned short h) {
  unsigned u = ((unsigned)h) << 16;
  return __builtin_bit_cast(float, u);
}

__device__ __forceinline__ void gload_lds16(const unsigned short* g, unsigned short* l) {
  __builtin_amdgcn_global_load_lds((__attribute__((address_space(1))) void*)(g),
                                   (__attribute__((address_space(3))) void*)(l), 16, 0, 0);
}

// ---------------- pack f32 -> bf16 (elementwise, 8/thread) ----------------
__global__ __launch_bounds__(256) void k_pack(const float* __restrict__ in,
                                              unsigned short* __restrict__ out, int n8) {
  int idx = blockIdx.x * blockDim.x + threadIdx.x;
  if (idx >= n8) return;
  const float* p = in + (size_t)idx * 8;
  floatx4 a = *(const floatx4*)p;
  floatx4 b = *(const floatx4*)(p + 4);
  bhalf8 r;
  r[0] = (short)f2bf(a[0]); r[1] = (short)f2bf(a[1]);
  r[2] = (short)f2bf(a[2]); r[3] = (short)f2bf(a[3]);
  r[4] = (short)f2bf(b[0]); r[5] = (short)f2bf(b[1]);
  r[6] = (short)f2bf(b[2]); r[7] = (short)f2bf(b[3]);
  *(bhalf8*)(out + (size_t)idx * 8) = r;
}

// ---------------- pack complex weight [O][I][2] f32 -> W' [2O][2I] bf16 ----
__global__ __launch_bounds__(256) void k_pack_w(const float* __restrict__ w,
                                                unsigned short* __restrict__ wp,
                                                int O, int I, float scale) {
  int idx = blockIdx.x * blockDim.x + threadIdx.x;
  int nI4 = I >> 2;
  if (idx >= O * nI4) return;
  int o = idx / nI4;
  int i4 = (idx - o * nI4) * 4;
  const float* src = w + ((size_t)o * I + i4) * 2;
  floatx4 a = *(const floatx4*)src;
  floatx4 b = *(const floatx4*)(src + 4);
  a *= scale; b *= scale;
  bhalf8 r0, r1;
  r0[0] = (short)f2bf(a[0]); r0[1] = (short)f2bf(-a[1]);
  r0[2] = (short)f2bf(a[2]); r0[3] = (short)f2bf(-a[3]);
  r0[4] = (short)f2bf(b[0]); r0[5] = (short)f2bf(-b[1]);
  r0[6] = (short)f2bf(b[2]); r0[7] = (short)f2bf(-b[3]);
  r1[0] = (short)f2bf(a[1]); r1[1] = (short)f2bf(a[0]);
  r1[2] = (short)f2bf(a[3]); r1[3] = (short)f2bf(a[2]);
  r1[4] = (short)f2bf(b[1]); r1[5] = (short)f2bf(b[0]);
  r1[6] = (short)f2bf(b[3]); r1[7] = (short)f2bf(b[2]);
  size_t I2 = (size_t)I * 2;
  *(bhalf8*)(wp + (size_t)(2 * o) * I2 + 2 * i4) = r0;
  *(bhalf8*)(wp + (size_t)(2 * o + 1) * I2 + 2 * i4) = r1;
}

// ---------------- concat bias [bq*s|bk|bv] -> 6144 f32 ----------------------
__global__ __launch_bounds__(256) void k_catbias(const float* __restrict__ a,
                                                 const float* __restrict__ b,
                                                 const float* __restrict__ c,
                                                 float* __restrict__ o, float qscale) {
  int i = blockIdx.x * 256 + threadIdx.x;
  float v = (i < 2048) ? a[i] * qscale : (i < 4096 ? b[i - 2048] : c[i - 4096]);
  o[i] = v;
}

// ---------------- GEMM 256x256, BK=64, 8 waves (2x4), single-region K-tile --
// (R6 structure — session-best: fc 145us, MfmaUtil 41%, 0 conflicts.)
// Per K-tile: { 8 gload_lds (tile T+1, issued FIRST) | fence | 24 ds_read +
// 64 MFMA (compiler-interleaved, lgkmcnt auto-paced) | vmcnt(0) | barrier }.
// Stage-at-start -> drain-at-end: landing window ~ full tile >> HBM latency.
// Swizzle: slot' = slot ^ (row&7) on 128B rows — measured 0-conflict.
// MODE: 0 = +bias, 1 = +bias+modReLU (lane-pair), 2 = raw.
template <int MODE>
__global__ __launch_bounds__(512, 2) void k_gemm256(
    const unsigned short* __restrict__ A0, const unsigned short* __restrict__ A1,
    int aSplit, int lda, const unsigned short* __restrict__ B, int ldb,
    const float* __restrict__ bias, unsigned short* __restrict__ C,
    int N, int K, long long zStrideC) {
  __shared__ unsigned short lds[65536];  // A bufs @0,16384; B bufs @32768,49152
  const int t = threadIdx.x, lane = t & 63, wid = t >> 6;
  const int wr = wid >> 2, wc = wid & 3;
  const int l15 = lane & 15, l4 = lane >> 4, s7 = l15 & 7;
  const int bn = blockIdx.x, bm = blockIdx.y, z = blockIdx.z;

  const unsigned short* Ab = ((bn < aSplit) ? A0 : A1) + (size_t)z * K;
  const unsigned short* Bb = B + (size_t)z * K;
  unsigned short* Cb = C + (size_t)z * zStrideC;

  const int pa = t >> 3;
  const int ua = ((t & 7) ^ (pa & 7)) * 8;
  const unsigned short* gA = Ab + (size_t)(bm * 256 + pa) * lda + ua;
  const unsigned short* gB = Bb + (size_t)(bn * 256 + pa) * ldb + ua;

  const int NT = K >> 6;
  floatx4 acc[8][4];
#pragma unroll
  for (int m = 0; m < 8; ++m)
#pragma unroll
    for (int n = 0; n < 4; ++n) acc[m][n] = (floatx4)0.f;

  // prologue: stage tile 0 into buf0
  {
    unsigned short* a0 = lds + wid * 512;
    unsigned short* b0 = lds + 32768 + wid * 512;
#pragma unroll
    for (int q = 0; q < 4; ++q) gload_lds16(gA + (size_t)q * 64 * lda, a0 + q * 4096);
#pragma unroll
    for (int q = 0; q < 4; ++q) gload_lds16(gB + (size_t)q * 64 * ldb, b0 + q * 4096);
  }
  asm volatile("s_waitcnt vmcnt(0)" ::: "memory");
  __builtin_amdgcn_s_barrier();

  for (int tk = 0; tk < NT; ++tk) {
    const unsigned short* lA = lds + (tk & 1) * 16384;
    const unsigned short* lB = lds + 32768 + (tk & 1) * 16384;
    const bool doS = (tk + 1 < NT);

    // ---- stage tile T+1 first (max landing window) ----
    if (doS) {
      unsigned short* sA = lds + ((tk + 1) & 1) * 16384 + wid * 512;
      unsigned short* sB = lds + 32768 + ((tk + 1) & 1) * 16384 + wid * 512;
      const size_t ko = (size_t)(tk + 1) * 64;
#pragma unroll
      for (int q = 0; q < 4; ++q) gload_lds16(gA + (size_t)q * 64 * lda + ko, sA + q * 4096);
#pragma unroll
      for (int q = 0; q < 4; ++q) gload_lds16(gB + (size_t)q * 64 * ldb + ko, sB + q * 4096);
    }
    asm volatile("" ::: "memory");  // pin gloads above the reads

    // ---- 24 ds_read_b128 + 64 MFMA: one region, compiler-paced ----
    bhalf8 af[8][2], bf[4][2];
#pragma unroll
    for (int m = 0; m < 8; ++m) {
      int p = wr * 128 + m * 16 + l15;
#pragma unroll
      for (int kk = 0; kk < 2; ++kk)
        af[m][kk] = *(const bhalf8*)&lA[p * 64 + (((kk << 2) + l4) ^ s7) * 8];
    }
#pragma unroll
    for (int n = 0; n < 4; ++n) {
      int p = wc * 64 + n * 16 + l15;
#pragma unroll
      for (int kk = 0; kk < 2; ++kk)
        bf[n][kk] = *(const bhalf8*)&lB[p * 64 + (((kk << 2) + l4) ^ s7) * 8];
    }
#pragma unroll
    for (int m = 0; m < 8; ++m)
#pragma unroll
      for (int n = 0; n < 4; ++n)
#pragma unroll
        for (int kk = 0; kk < 2; ++kk) acc[m][n] = MFMA16(af[m][kk], bf[n][kk], acc[m][n]);

    // ---- tile boundary: drain this tile's stages (landed ~a tile ago) ----
    if (doS) {
      asm volatile("s_waitcnt vmcnt(0)" ::: "memory");
      __builtin_amdgcn_s_barrier();
    }
  }

  const int r0 = bm * 256 + wr * 128 + l4 * 4;
  const int c0 = bn * 256 + wc * 64 + l15;
#pragma unroll
  for (int mi = 0; mi < 8; ++mi) {
    int row0 = r0 + mi * 16;
#pragma unroll
    for (int n = 0; n < 4; ++n) {
      int col = c0 + n * 16;
      float bv = (MODE == 2) ? 0.f : bias[col];
#pragma unroll
      for (int rr = 0; rr < 4; ++rr) {
        float v = acc[mi][n][rr] + bv;
        if (MODE == 1) {
          float o = __shfl_xor(v, 1, 64);
          float mag = sqrtf(v * v + o * o);
          v = (lane & 1) ? 0.5f * v : 0.5f * (v + mag);
        }
        Cb[(size_t)(row0 + rr) * N + col] = f2bf(v);
      }
    }
  }
}

// ---------------- complex flash attention (swapped QK^T, in-lane softmax) ---
// QKV fused rows: [tok][0..2047]=Q(pre-scaled), [2048..4095]=K, [4096..6143]=V.
// VtB eliminated: vb = sign(l15) * Vt[row^1] (same-cost read + const sign mask).
__global__ __launch_bounds__(256) void k_attn(const unsigned short* __restrict__ qkv,
                                              unsigned short* __restrict__ O) {
  __shared__ unsigned short Ks[32][136];
  __shared__ unsigned short Vt[128][40];
  __shared__ unsigned short Ps[4][2][16][40];

  const int t = threadIdx.x, lane = t & 63, wave = t >> 6;
  const int l15 = lane & 15, l4 = lane >> 4;
  const int bid = blockIdx.x;
  const int qt = bid & 7, h = (bid >> 3) & 15, b = bid >> 7;
  const int colbase = h * 128;
  const int qrow0 = b * 512 + qt * 64 + wave * 16;
  const unsigned smask = (l15 & 1) ? 0u : 0x80008000u;  // even feature: -V[j+1]

  bhalf8 qf[4];
  {
    const unsigned short* qp = qkv + (size_t)(qrow0 + l15) * 6144 + colbase + l4 * 8;
#pragma unroll
    for (int ks = 0; ks < 4; ks++) qf[ks] = *(const bhalf8*)(qp + ks * 32);
  }

  float m_s[2] = {-1e30f, -1e30f}, l_s[2] = {0.f, 0.f};
  floatx4 oacc[2][8];
#pragma unroll
  for (int c = 0; c < 2; c++)
#pragma unroll
    for (int n = 0; n < 8; n++) oacc[c][n] = (floatx4)0.f;

  for (int kb = 0; kb < 16; kb++) {
    __syncthreads();
#pragma unroll
    for (int s = 0; s < 2; s++) {
      int c = t + s * 256;
      int kr = c >> 4, jc = (c & 15) * 8;
      *(bhalf8*)&Ks[kr][jc] =
          *(const bhalf8*)(qkv + (size_t)(b * 512 + kb * 32 + kr) * 6144 + 2048 + colbase + jc);
    }
#pragma unroll
    for (int s = 0; s < 2; s++) {
      int c = t + s * 256;
      int kr = c & 31, j0 = (c >> 5) * 8;
      bhalf8 vv = *(const bhalf8*)(qkv + (size_t)(b * 512 + kb * 32 + kr) * 6144 + 4096 +
                                   colbase + j0);
#pragma unroll
      for (int i2 = 0; i2 < 8; i2++) Vt[j0 + i2][kr] = (unsigned short)vv[i2];
    }
    __syncthreads();

    floatx4 sacc[2][2];
#pragma unroll
    for (int c = 0; c < 2; c++) { sacc[c][0] = (floatx4)0.f; sacc[c][1] = (floatx4)0.f; }
#pragma unroll
    for (int ks = 0; ks < 4; ks++) {
#pragma unroll
      for (int n = 0; n < 2; n++) {
        bhalf8 kf = *(const bhalf8*)&Ks[n * 16 + l15][ks * 32 + l4 * 8];
        uintx4 ku = __builtin_bit_cast(uintx4, kf);
        uintx4 kneg = ku ^ 0x80000000u;
        uintx4 kswp = (ku >> 16) | (ku << 16);
        sacc[0][n] = MFMA16(__builtin_bit_cast(bhalf8, kneg), qf[ks], sacc[0][n]);
        sacc[1][n] = MFMA16(__builtin_bit_cast(bhalf8, kswp), qf[ks], sacc[1][n]);
      }
    }

    float pmax[2];
#pragma unroll
    for (int c = 0; c < 2; c++) {
      float a = fmaxf(fmaxf(sacc[c][0][0], sacc[c][0][1]), fmaxf(sacc[c][0][2], sacc[c][0][3]));
      float d = fmaxf(fmaxf(sacc[c][1][0], sacc[c][1][1]), fmaxf(sacc[c][1][2], sacc[c][1][3]));
      float v = fmaxf(a, d);
      v = fmaxf(v, __shfl_xor(v, 16, 64));
      v = fmaxf(v, __shfl_xor(v, 32, 64));
      pmax[c] = v;
    }
    if (__any((pmax[0] > m_s[0] + 8.f) || (pmax[1] > m_s[1] + 8.f))) {
#pragma unroll
      for (int c = 0; c < 2; c++) {
        float mnew = fmaxf(m_s[c], pmax[c]);
        float cr = __expf(m_s[c] - mnew);
        l_s[c] *= cr;
        m_s[c] = mnew;
        float crq[4];
#pragma unroll
        for (int r = 0; r < 4; r++) crq[r] = __shfl(cr, l4 * 4 + r, 64);
#pragma unroll
        for (int nn = 0; nn < 8; nn++)
#pragma unroll
          for (int r = 0; r < 4; r++) oacc[c][nn][r] *= crq[r];
      }
    }
#pragma unroll
    for (int c = 0; c < 2; c++) {
      float p[8], sum = 0.f;
#pragma unroll
      for (int n = 0; n < 2; n++)
#pragma unroll
        for (int r = 0; r < 4; r++) {
          float e = __expf(sacc[c][n][r] - m_s[c]);
          p[n * 4 + r] = e;
          sum += e;
        }
      sum += __shfl_xor(sum, 16, 64);
      sum += __shfl_xor(sum, 32, 64);
      l_s[c] += sum;
#pragma unroll
      for (int n = 0; n < 2; n++) {
        unsigned pk0, pk1;
        asm("v_cvt_pk_bf16_f32 %0, %1, %2" : "=v"(pk0) : "v"(p[n * 4 + 0]), "v"(p[n * 4 + 1]));
        asm("v_cvt_pk_bf16_f32 %0, %1, %2" : "=v"(pk1) : "v"(p[n * 4 + 2]), "v"(p[n * 4 + 3]));
        *(unsigned*)&Ps[wave][c][l15][n * 16 + l4 * 4] = pk0;
        *(unsigned*)&Ps[wave][c][l15][n * 16 + l4 * 4 + 2] = pk1;
      }
    }
    asm volatile("s_waitcnt lgkmcnt(0)" ::: "memory");
    __builtin_amdgcn_sched_barrier(0);

    bhalf8 par = *(const bhalf8*)&Ps[wave][0][l15][l4 * 8];
    bhalf8 pai = *(const bhalf8*)&Ps[wave][1][l15][l4 * 8];
    __builtin_amdgcn_s_setprio(1);
#pragma unroll
    for (int nn = 0; nn < 8; nn++) {
      bhalf8 vf = *(const bhalf8*)&Vt[nn * 16 + l15][l4 * 8];
      uintx4 vbu = *(const uintx4*)&Vt[nn * 16 + (l15 ^ 1)][l4 * 8];
      vbu ^= smask;
      oacc[0][nn] = MFMA16(par, vf, oacc[0][nn]);
      oacc[1][nn] = MFMA16(pai, __builtin_bit_cast(bhalf8, vbu), oacc[1][nn]);
    }
    __builtin_amdgcn_s_setprio(0);
  }

  float inv0[4], inv1[4];
#pragma unroll
  for (int r = 0; r < 4; r++) {
    inv0[r] = 1.f / __shfl(l_s[0], l4 * 4 + r, 64);
    inv1[r] = 1.f / __shfl(l_s[1], l4 * 4 + r, 64);
  }
#pragma unroll
  for (int nn = 0; nn < 8; nn++) {
#pragma unroll
    for (int r = 0; r < 4; r++) {
      float o = oacc[0][nn][r] * inv0[r] + oacc[1][nn][r] * inv1[r];
      int row = qrow0 + l4 * 4 + r;
      int col = colbase + nn * 16 + l15;
      O[(size_t)row * 2048 + col] = f2bf(o);
    }
  }
}

// ---------------- block reduction of 4 values across 256 threads ------------
__device__ __forceinline__ void block_reduce_4(float* v, float* sbuf, int t) {
  int lane = t & 63, wave = t >> 6;
#pragma unroll
  for (int i = 0; i < 4; i++) {
    float x = v[i];
#pragma unroll
    for (int off = 32; off > 0; off >>= 1) x += __shfl_xor(x, off, 64);
    if (lane == 0) sbuf[wave * 4 + i] = x;
  }
  __syncthreads();
#pragma unroll
  for (int i = 0; i < 4; i++) v[i] = sbuf[i] + sbuf[4 + i] + sbuf[8 + i] + sbuf[12 + i];
  __syncthreads();
}

// ---------------- post-attention: (O+q) -> LN0 -> (+x) -> LN1 ---------------
__global__ __launch_bounds__(256) void k_ln_attn(const unsigned short* __restrict__ O,
                                                 const float* __restrict__ qin,
                                                 const float* __restrict__ xin,
                                                 const float* __restrict__ g,
                                                 const float* __restrict__ bb,
                                                 float* __restrict__ xr2,
                                                 unsigned short* __restrict__ xr2b) {
  __shared__ float sbuf[16];
  const int row = blockIdx.x, t = threadIdx.x;
  const size_t base = (size_t)row * 2048;
  float tr[4], ti[4], acc[4] = {0.f, 0.f, 0.f, 0.f};
#pragma unroll
  for (int k = 0; k < 4; k++) {
    int d = k * 256 + t;
    unsigned op = *(const unsigned*)(O + base + 2 * d);
    floatx2 qp = *(const floatx2*)(qin + base + 2 * d);
    float a = bf2f((unsigned short)(op & 0xffffu)) + qp[0];
    float c = bf2f((unsigned short)(op >> 16)) + qp[1];
    tr[k] = a; ti[k] = c;
    acc[0] += a; acc[1] += a * a; acc[2] += c; acc[3] += c * c;
  }
  block_reduce_4(acc, sbuf, t);
  float mr = acc[0] * (1.f / 1024.f), vr = acc[1] * (1.f / 1024.f) - mr * mr;
  float mi = acc[2] * (1.f / 1024.f), vi = acc[3] * (1.f / 1024.f) - mi * mi;
  float ir = rsqrtf(vr + 1e-5f), ii = rsqrtf(vi + 1e-5f);
  float ur[4], ui[4], a2[4] = {0.f, 0.f, 0.f, 0.f};
#pragma unroll
  for (int k = 0; k < 4; k++) {
    int d = k * 256 + t;
    float u_r = (tr[k] - mr) * ir * g[d] + bb[d];
    float u_i = (ti[k] - mi) * ii * g[1024 + d] + bb[1024 + d];
    floatx2 xp = *(const floatx2*)(xin + base + 2 * d);
    float v_r = xp[0] + u_r, v_i = xp[1] + u_i;
    ur[k] = v_r; ui[k] = v_i;
    a2[0] += v_r; a2[1] += v_r * v_r; a2[2] += v_i; a2[3] += v_i * v_i;
  }
  block_reduce_4(a2, sbuf, t);
  float mr2 = a2[0] * (1.f / 1024.f), vr2 = a2[1] * (1.f / 1024.f) - mr2 * mr2;
  float mi2 = a2[2] * (1.f / 1024.f), vi2 = a2[3] * (1.f / 1024.f) - mi2 * mi2;
  float ir2 = rsqrtf(vr2 + 1e-5f), ii2 = rsqrtf(vi2 + 1e-5f);
#pragma unroll
  for (int k = 0; k < 4; k++) {
    int d = k * 256 + t;
    float w_r = (ur[k] - mr2) * ir2 * g[2048 + d] + bb[2048 + d];
    float w_i = (ui[k] - mi2) * ii2 * g[3072 + d] + bb[3072 + d];
    floatx2 o; o[0] = w_r; o[1] = w_i;
    *(floatx2*)(xr2 + base + 2 * d) = o;
    unsigned pk = ((unsigned)f2bf(w_i) << 16) | (unsigned)f2bf(w_r);
    *(unsigned*)(xr2b + base + 2 * d) = pk;
  }
}

// ---------------- final: (xr2 + p0 + p1 + bias) -> LN2 -> out ---------------
__global__ __launch_bounds__(256) void k_ln_final(const unsigned short* __restrict__ P0,
                                                  const unsigned short* __restrict__ P1,
                                                  const float* __restrict__ xr2,
                                                  const float* __restrict__ pbias,
                                                  const float* __restrict__ g,
                                                  const float* __restrict__ bb,
                                                  float* __restrict__ out) {
  __shared__ float sbuf[16];
  const int row = blockIdx.x, t = threadIdx.x;
  const size_t base = (size_t)row * 2048;
  float tr[4], ti[4], acc[4] = {0.f, 0.f, 0.f, 0.f};
#pragma unroll
  for (int k = 0; k < 4; k++) {
    int d = k * 256 + t;
    unsigned m0 = *(const unsigned*)(P0 + base + 2 * d);
    unsigned m1 = *(const unsigned*)(P1 + base + 2 * d);
    floatx2 xp = *(const floatx2*)(xr2 + base + 2 * d);
    floatx2 bp = *(const floatx2*)(pbias + 2 * d);
    float a = xp[0] + bp[0] + bf2f((unsigned short)(m0 & 0xffffu)) +
              bf2f((unsigned short)(m1 & 0xffffu));
    float c = xp[1] + bp[1] + bf2f((unsigned short)(m0 >> 16)) +
              bf2f((unsigned short)(m1 >> 16));
    tr[k] = a; ti[k] = c;
    acc[0] += a; acc[1] += a * a; acc[2] += c; acc[3] += c * c;
  }
  block_reduce_4(acc, sbuf, t);
  float mr = acc[0] * (1.f / 1024.f), vr = acc[1] * (1.f / 1024.f) - mr * mr;
  float mi = acc[2] * (1.f / 1024.f), vi = acc[3] * (1.f / 1024.f) - mi * mi;
  float ir = rsqrtf(vr + 1e-5f), ii = rsqrtf(vi + 1e-5f);
#pragma unroll
  for (int k = 0; k < 4; k++) {
    int d = k * 256 + t;
    float w_r = (tr[k] - mr) * ir * g[4096 + d] + bb[4096 + d];
    float w_i = (ti[k] - mi) * ii * g[5120 + d] + bb[5120 + d];
    floatx2 o; o[0] = w_r; o[1] = w_i;
    *(floatx2*)(out + base + 2 * d) = o;
  }
}

extern "C" void kernel_launch(void* const* d_in, const int* in_sizes, int n_in,
                              void* d_out, int out_size, void* d_ws, size_t ws_size,
                              hipStream_t stream) {
  const float* x   = (const float*)d_in[0];
  const float* qy  = (const float*)d_in[1];
  const float* wq  = (const float*)d_in[2];
  const float* bq  = (const float*)d_in[3];
  const float* wk  = (const float*)d_in[4];
  const float* bk  = (const float*)d_in[5];
  const float* wv  = (const float*)d_in[6];
  const float* bv  = (const float*)d_in[7];
  const float* wfc = (const float*)d_in[8];
  const float* bfc = (const float*)d_in[9];
  const float* wpj = (const float*)d_in[10];
  const float* bpj = (const float*)d_in[11];
  const float* lng = (const float*)d_in[12];
  const float* lnb = (const float*)d_in[13];

  const size_t SZ_TOK = (size_t)4096 * 2048;
  unsigned short* ws0  = (unsigned short*)d_ws;
  unsigned short* xqb  = ws0;
  unsigned short* xb   = xqb + SZ_TOK;
  unsigned short* wp   = xb + SZ_TOK;
  unsigned short* QKVb = wp + 2 * SZ_TOK;
  unsigned short* hb   = QKVb + 3 * SZ_TOK;
  float* cbias = (float*)(wp + SZ_TOK + SZ_TOK / 2);
  unsigned short* Ob  = xqb;
  float*          xr2 = (float*)QKVb;
  unsigned short* x2b = QKVb + 2 * SZ_TOK;
  const int BIG = 1 << 30;

  const int n8 = (int)(SZ_TOK / 8);
  k_pack<<<n8 / 256, 256, 0, stream>>>(qy, xqb, n8);
  k_pack<<<n8 / 256, 256, 0, stream>>>(x, xb, n8);

  // fused QKV: B = [Wq'*0.125; Wk'; Wv'] (N=6144); A = xqb for bn<8, xb else
  k_pack_w<<<1024, 256, 0, stream>>>(wq, wp, 1024, 1024, 0.125f);
  k_pack_w<<<1024, 256, 0, stream>>>(wk, wp + (size_t)2048 * 2048, 1024, 1024, 1.f);
  k_pack_w<<<1024, 256, 0, stream>>>(wv, wp + (size_t)4096 * 2048, 1024, 1024, 1.f);
  k_catbias<<<24, 256, 0, stream>>>(bq, bk, bv, cbias, 0.125f);
  k_gemm256<0><<<dim3(24, 16, 1), 512, 0, stream>>>(xqb, xb, 8, 2048, wp, 2048, cbias,
                                                    QKVb, 6144, 2048, 0);

  k_attn<<<1024, 256, 0, stream>>>(QKVb, Ob);
  k_ln_attn<<<4096, 256, 0, stream>>>(Ob, qy, x, lng, lnb, xr2, x2b);

  // fc + fused modReLU: M=4096, N=8192, K=2048
  k_pack_w<<<4096, 256, 0, stream>>>(wfc, wp, 4096, 1024, 1.f);
  k_gemm256<1><<<dim3(32, 16, 1), 512, 0, stream>>>(x2b, x2b, BIG, 2048, wp, 2048, bfc,
                                                    hb, 8192, 2048, 0);

  // proj split-K=2: z in {0,1}, K=4096 each, raw bf16 partials into xqb/xb
  k_pack_w<<<4096, 256, 0, stream>>>(wpj, wp, 1024, 4096, 1.f);
  k_gemm256<2><<<dim3(8, 16, 2), 512, 0, stream>>>(hb, hb, BIG, 8192, wp, 8192, bpj,
                                                   xqb, 2048, 4096, (long long)SZ_TOK);

  k_ln_final<<<4096, 256, 0, stream>>>(xqb, xb, xr2, bpj, lng, lnb, (float*)d_out);
}